// Round 1
// baseline (154.964 us; speedup 1.0000x reference)
//
#include <hip/hip_runtime.h>
#include <hip/hip_bf16.h>

typedef unsigned short u16;
typedef unsigned int u32;
typedef __bf16 bf16x8 __attribute__((ext_vector_type(8)));
typedef float f32x4 __attribute__((ext_vector_type(4)));

#define NSPK 1024
#define NUTT 20
#define DEMB 512
#define NROW (NSPK * NUTT)   // 20480

__device__ __forceinline__ u16 f2bf(float x) {
    union { float f; u32 u; } v; v.f = x;
    u32 r = (v.u + 0x7fffu + ((v.u >> 16) & 1u)) >> 16;   // RNE
    return (u16)r;
}
__device__ __forceinline__ float bf2f(u16 h) {
    union { float f; u32 u; } v; v.u = ((u32)h) << 16;
    return v.f;
}

// ---------------------------------------------------------------------------
// Kernel 1: per-speaker prep. One block (256 thr) per speaker.
// Each thread owns dims d0=2t, 2t+1. Emits bf16 e_n rows (A), bf16 c_n (Bc),
// fp32 diag (leave-one-out cosine), fp32 csdiag (e_n . own c_n, bf16-domain).
// ---------------------------------------------------------------------------
__global__ __launch_bounds__(256) void prep(const float* __restrict__ E,
                                            u16* __restrict__ A,
                                            u16* __restrict__ Bc,
                                            float* __restrict__ diag,
                                            float* __restrict__ csd) {
    __shared__ float s_red[16];
    const int n = blockIdx.x;
    const int t = threadIdx.x;
    const int lane = t & 63, wv = t >> 6;
    const int d0 = t * 2;
    const float* En = E + (size_t)n * (NUTT * DEMB);

    // load all 20 utterance values for this thread's 2 dims into registers
    float2 ev[NUTT];
    float sx = 0.f, sy = 0.f;
#pragma unroll
    for (int m = 0; m < NUTT; ++m) {
        ev[m] = *(const float2*)(En + m * DEMB + d0);
        sx += ev[m].x; sy += ev[m].y;
    }

    // centroid norm (full D reduce)
    float c0 = sx * (1.0f / NUTT), c1 = sy * (1.0f / NUTT);
    float p = c0 * c0 + c1 * c1;
#pragma unroll
    for (int o = 32; o; o >>= 1) p += __shfl_xor(p, o);
    if (lane == 0) s_red[wv] = p;
    __syncthreads();
    p = s_red[0] + s_red[1] + s_red[2] + s_red[3];
    float rc = 1.0f / fmaxf(sqrtf(p), 1e-8f);
    u16 cb0 = f2bf(c0 * rc), cb1 = f2bf(c1 * rc);
    *(u32*)(Bc + (size_t)n * DEMB + d0) = (u32)cb0 | ((u32)cb1 << 16);
    const float cx = bf2f(cb0), cy = bf2f(cb1);   // bf16-rounded centroid (matmul domain)

    for (int m = 0; m < NUTT; ++m) {
        const float ex = ev[m].x, ey = ev[m].y;
        const float xx = sx - ex, xy = sy - ey;   // (sums - e), unscaled LOO centroid
        float pee = ex * ex + ey * ey;
        float pex = ex * xx + ey * xy;
        float pxx = xx * xx + xy * xy;
        float pec = ex * cx + ey * cy;
#pragma unroll
        for (int o = 32; o; o >>= 1) {
            pee += __shfl_xor(pee, o); pex += __shfl_xor(pex, o);
            pxx += __shfl_xor(pxx, o); pec += __shfl_xor(pec, o);
        }
        __syncthreads();   // protect s_red from previous iteration readers
        if (lane == 0) {
            s_red[wv * 4 + 0] = pee; s_red[wv * 4 + 1] = pex;
            s_red[wv * 4 + 2] = pxx; s_red[wv * 4 + 3] = pec;
        }
        __syncthreads();
        pee = s_red[0] + s_red[4] + s_red[8] + s_red[12];
        pex = s_red[1] + s_red[5] + s_red[9] + s_red[13];
        pxx = s_red[2] + s_red[6] + s_red[10] + s_red[14];
        pec = s_red[3] + s_red[7] + s_red[11] + s_red[15];

        const float rne = 1.0f / fmaxf(sqrtf(pee), 1e-8f);
        // ce_n = (s-e)/19 / max(||s-e||/19, 1e-8)  ->  (s-e)/max(||s-e||, 19e-8)
        const float dg = pex * rne / fmaxf(sqrtf(pxx), 1.9e-7f);

        u16 a0 = f2bf(ex * rne), a1 = f2bf(ey * rne);
        *(u32*)(A + ((size_t)(n * NUTT + m)) * DEMB + d0) = (u32)a0 | ((u32)a1 << 16);
        if (t == 0) {
            diag[n * NUTT + m] = dg;
            csd[n * NUTT + m] = pec * rne;   // approx of bf16 matmul diagonal (err ~1e-4, cancels)
        }
    }
}

// ---------------------------------------------------------------------------
// Kernel 2: bf16 MFMA GEMM [20480x512] x [1024x512]^T with fused
// exp(w*(cs+1e-6)+b) row-sum epilogue -> atomicAdd rowsum[20480].
// 128x128 tile, BK=32, 4 waves (2x2 of 64x64), global_load_lds width 16,
// XOR k-chunk swizzle so ds_read_b128 is <=2-way bank-conflicted.
// ---------------------------------------------------------------------------
__device__ __forceinline__ void async_copy16(const void* g, void* l) {
    __builtin_amdgcn_global_load_lds(
        (const __attribute__((address_space(1))) void*)g,
        (__attribute__((address_space(3))) void*)l, 16, 0, 0);
}

__global__ __launch_bounds__(256) void gemm_exp(const u16* __restrict__ A,
                                                const u16* __restrict__ Bc,
                                                const float* __restrict__ wp,
                                                const float* __restrict__ bp,
                                                float* __restrict__ rowsum) {
    __shared__ u16 As[128 * 32];   // 8 KB, row-major [row][k], k-chunks XOR-swizzled
    __shared__ u16 Bs[128 * 32];   // 8 KB, [col][k]
    const int t = threadIdx.x;
    const int lane = t & 63, wv = t >> 6;
    const int ml = lane & 15, q = lane >> 4;
    const int wm = wv >> 1, wn = wv & 1;
    const int tileM = blockIdx.x;    // 0..159
    const int tileN = blockIdx.y;    // 0..7

    const float w = *wp, bb = *bp;

    // staging chunk indices: chunk c -> local row r=c>>2, stored k-slot c&3,
    // global k-group = (c&3) ^ ((r>>1)&3)
    const int c0 = t, c1 = t + 256;
    const int r0 = c0 >> 2, kg0 = (c0 & 3) ^ ((r0 >> 1) & 3);
    const int r1 = c1 >> 2, kg1 = (c1 & 3) ^ ((r1 >> 1) & 3);
    const u16* Ag = A + (size_t)tileM * 128 * DEMB;
    const u16* Bg = Bc + (size_t)tileN * 128 * DEMB;
    u16* as0 = As + c0 * 8; u16* as1 = As + c1 * 8;
    u16* bs0 = Bs + c0 * 8; u16* bs1 = Bs + c1 * 8;

    // fragment read offsets (u16 units), swizzle-matched
    int ar[4], br[4];
#pragma unroll
    for (int i = 0; i < 4; ++i) {
        int r = wm * 64 + i * 16 + ml;
        ar[i] = r * 32 + ((q ^ ((r >> 1) & 3)) << 3);
        int c = wn * 64 + i * 16 + ml;
        br[i] = c * 32 + ((q ^ ((c >> 1) & 3)) << 3);
    }

    f32x4 acc[4][4];
#pragma unroll
    for (int i = 0; i < 4; ++i)
#pragma unroll
        for (int j = 0; j < 4; ++j) acc[i][j] = (f32x4){0.f, 0.f, 0.f, 0.f};

    for (int kt = 0; kt < DEMB; kt += 32) {
        __syncthreads();   // previous tile fully consumed before overwrite
        async_copy16(Ag + (size_t)r0 * DEMB + kt + kg0 * 8, as0);
        async_copy16(Ag + (size_t)r1 * DEMB + kt + kg1 * 8, as1);
        async_copy16(Bg + (size_t)r0 * DEMB + kt + kg0 * 8, bs0);
        async_copy16(Bg + (size_t)r1 * DEMB + kt + kg1 * 8, bs1);
        __syncthreads();   // drains vmcnt (global_load_lds) per barrier semantics

        bf16x8 af[4], bfv[4];
#pragma unroll
        for (int i = 0; i < 4; ++i) af[i] = *(const bf16x8*)(As + ar[i]);
#pragma unroll
        for (int j = 0; j < 4; ++j) bfv[j] = *(const bf16x8*)(Bs + br[j]);
#pragma unroll
        for (int i = 0; i < 4; ++i)
#pragma unroll
            for (int j = 0; j < 4; ++j)
                acc[i][j] = __builtin_amdgcn_mfma_f32_16x16x32_bf16(af[i], bfv[j], acc[i][j], 0, 0, 0);
    }

    // epilogue: exp + row-sum. C/D layout: col = lane&15, row = q*4 + reg.
#pragma unroll
    for (int i = 0; i < 4; ++i) {
        float s0 = 0.f, s1 = 0.f, s2 = 0.f, s3 = 0.f;
#pragma unroll
        for (int j = 0; j < 4; ++j) {
            s0 += __expf(fmaf(w, acc[i][j][0] + 1e-6f, bb));
            s1 += __expf(fmaf(w, acc[i][j][1] + 1e-6f, bb));
            s2 += __expf(fmaf(w, acc[i][j][2] + 1e-6f, bb));
            s3 += __expf(fmaf(w, acc[i][j][3] + 1e-6f, bb));
        }
#pragma unroll
        for (int o = 1; o < 16; o <<= 1) {   // reduce over the 16 cols (lanes within quad)
            s0 += __shfl_xor(s0, o); s1 += __shfl_xor(s1, o);
            s2 += __shfl_xor(s2, o); s3 += __shfl_xor(s3, o);
        }
        if (ml < 4) {
            float sv = (ml == 0) ? s0 : (ml == 1) ? s1 : (ml == 2) ? s2 : s3;
            int grow = tileM * 128 + wm * 64 + i * 16 + q * 4 + ml;
            atomicAdd(&rowsum[grow], sv);
        }
    }
}

// ---------------------------------------------------------------------------
// Kernel 3: per-row diagonal fixup + log + final reduction.
// ---------------------------------------------------------------------------
__global__ __launch_bounds__(256) void finalize(const float* __restrict__ rowsum,
                                                const float* __restrict__ diag,
                                                const float* __restrict__ csd,
                                                const float* __restrict__ wp,
                                                const float* __restrict__ bp,
                                                float* __restrict__ out) {
    __shared__ float s_red[4];
    const int r = blockIdx.x * 256 + threadIdx.x;   // 80*256 == 20480 exactly
    const float w = *wp, bb = *bp;
    const float dg = diag[r];
    const float pos = fmaf(w, dg + 1e-6f, bb);
    const float S = rowsum[r] - __expf(fmaf(w, csd[r] + 1e-6f, bb)) + __expf(pos);
    float term = logf(S + 1e-6f) - pos;
    const int lane = threadIdx.x & 63, wv = threadIdx.x >> 6;
#pragma unroll
    for (int o = 32; o; o >>= 1) term += __shfl_xor(term, o);
    if (lane == 0) s_red[wv] = term;
    __syncthreads();
    if (threadIdx.x == 0) atomicAdd(out, s_red[0] + s_red[1] + s_red[2] + s_red[3]);
}

extern "C" void kernel_launch(void* const* d_in, const int* in_sizes, int n_in,
                              void* d_out, int out_size, void* d_ws, size_t ws_size,
                              hipStream_t stream) {
    const float* E = (const float*)d_in[0];
    const float* wp = (const float*)d_in[1];
    const float* bp = (const float*)d_in[2];
    float* out = (float*)d_out;

    char* ws = (char*)d_ws;
    u16* A    = (u16*)(ws);                       // 20480*512*2 = 20,971,520 B
    u16* Bc   = (u16*)(ws + 20971520);            //  1024*512*2 =  1,048,576 B
    float* dg = (float*)(ws + 22020096);          // 20480*4
    float* cs = (float*)(ws + 22102016);          // 20480*4
    float* rs = (float*)(ws + 22183936);          // 20480*4

    hipMemsetAsync(rs, 0, NROW * sizeof(float), stream);
    hipMemsetAsync(out, 0, sizeof(float), stream);
    prep<<<NSPK, 256, 0, stream>>>(E, A, Bc, dg, cs);
    gemm_exp<<<dim3(160, 8), 256, 0, stream>>>(A, Bc, wp, bp, rs);
    finalize<<<80, 256, 0, stream>>>(rs, dg, cs, wp, bp, out);
}

// Round 2
// 124.875 us; speedup vs baseline: 1.2410x; 1.2410x over previous
//
#include <hip/hip_runtime.h>
#include <hip/hip_bf16.h>

typedef unsigned short u16;
typedef unsigned int u32;
typedef __bf16 bf16x8 __attribute__((ext_vector_type(8)));
typedef float f32x4 __attribute__((ext_vector_type(4)));

#define NSPK 1024
#define NUTT 20
#define DEMB 512
#define NROW (NSPK * NUTT)   // 20480

__device__ __forceinline__ u16 f2bf(float x) {
    union { float f; u32 u; } v; v.f = x;
    u32 r = (v.u + 0x7fffu + ((v.u >> 16) & 1u)) >> 16;   // RNE
    return (u16)r;
}

// ---------------------------------------------------------------------------
// Kernel A: per-speaker sums. One block (256 thr) per speaker; ONE reduction
// round (vs 20 in R1's prep). Emits fp32 sums row S, bf16 centroid Bc,
// per-speaker scalars ssg = {||s||^2, rc/20}. Also zeroes rowsum and out.
// ---------------------------------------------------------------------------
__global__ __launch_bounds__(256) void sums_k(const float* __restrict__ E,
                                              float* __restrict__ S,
                                              u16* __restrict__ Bc,
                                              float* __restrict__ ssg,
                                              float* __restrict__ rs,
                                              float* __restrict__ out) {
    __shared__ float s_red[4];
    const int n = blockIdx.x;
    const int t = threadIdx.x;
    const int lane = t & 63, wv = t >> 6;
    const int d0 = t * 2;
    const float* En = E + (size_t)n * (NUTT * DEMB);

    float sx = 0.f, sy = 0.f;
#pragma unroll
    for (int m = 0; m < NUTT; ++m) {
        float2 v = *(const float2*)(En + m * DEMB + d0);
        sx += v.x; sy += v.y;
    }
    *(float2*)(S + (size_t)n * DEMB + d0) = make_float2(sx, sy);

    const float c0 = sx * (1.0f / NUTT), c1 = sy * (1.0f / NUTT);
    float p = c0 * c0 + c1 * c1;
#pragma unroll
    for (int o = 32; o; o >>= 1) p += __shfl_xor(p, o);
    if (lane == 0) s_red[wv] = p;
    __syncthreads();
    p = s_red[0] + s_red[1] + s_red[2] + s_red[3];          // ||c||^2
    const float rc = 1.0f / fmaxf(sqrtf(p), 1e-8f);
    const u16 cb0 = f2bf(c0 * rc), cb1 = f2bf(c1 * rc);
    *(u32*)(Bc + (size_t)n * DEMB + d0) = (u32)cb0 | ((u32)cb1 << 16);

    if (t == 0) {
        ssg[2 * n + 0] = p * (float)(NUTT * NUTT);          // ||s||^2
        ssg[2 * n + 1] = rc * (1.0f / NUTT);                // e.c = es * rne * (rc/20)
    }
    if (t < NUTT) rs[n * NUTT + t] = 0.f;
    if (n == 0 && t == 0) out[0] = 0.f;
}

// ---------------------------------------------------------------------------
// Kernel B: one WAVE per (n,m) row — zero barriers, one 12-step butterfly.
// lane owns dims 8l..8l+7. Emits bf16 e_n row (A), fp32 diag, fp32 csd.
// ---------------------------------------------------------------------------
__global__ __launch_bounds__(256) void rowprep_k(const float* __restrict__ E,
                                                 const float* __restrict__ S,
                                                 const float* __restrict__ ssg,
                                                 u16* __restrict__ A,
                                                 float* __restrict__ diag,
                                                 float* __restrict__ csd) {
    const int lane = threadIdx.x & 63;
    const int r = blockIdx.x * 4 + (threadIdx.x >> 6);      // 5120*4 == 20480
    const int n = r / NUTT;

    const float* e = E + (size_t)r * DEMB + lane * 8;
    const float* s = S + (size_t)n * DEMB + lane * 8;
    const float4 e0 = *(const float4*)(e), e1 = *(const float4*)(e + 4);
    const float4 s0 = *(const float4*)(s), s1 = *(const float4*)(s + 4);

    float ee = e0.x*e0.x + e0.y*e0.y + e0.z*e0.z + e0.w*e0.w
             + e1.x*e1.x + e1.y*e1.y + e1.z*e1.z + e1.w*e1.w;
    float es = e0.x*s0.x + e0.y*s0.y + e0.z*s0.z + e0.w*s0.w
             + e1.x*s1.x + e1.y*s1.y + e1.z*s1.z + e1.w*s1.w;
#pragma unroll
    for (int o = 32; o; o >>= 1) { ee += __shfl_xor(ee, o); es += __shfl_xor(es, o); }

    const float ss = ssg[2 * n + 0], g = ssg[2 * n + 1];
    const float rne = 1.0f / fmaxf(sqrtf(ee), 1e-8f);
    const float pxx = ss - 2.f * es + ee;                   // ||s-e||^2, no cancellation risk
    const float dg = (es - ee) * rne / fmaxf(sqrtf(pxx), 1.9e-7f);

    union { u16 h[8]; uint4 q; } pk;
    pk.h[0] = f2bf(e0.x * rne); pk.h[1] = f2bf(e0.y * rne);
    pk.h[2] = f2bf(e0.z * rne); pk.h[3] = f2bf(e0.w * rne);
    pk.h[4] = f2bf(e1.x * rne); pk.h[5] = f2bf(e1.y * rne);
    pk.h[6] = f2bf(e1.z * rne); pk.h[7] = f2bf(e1.w * rne);
    ((uint4*)(A + (size_t)r * DEMB))[lane] = pk.q;

    if (lane == 0) {
        diag[r] = dg;
        csd[r] = es * g * rne;
    }
}

// ---------------------------------------------------------------------------
// Kernel 2: bf16 MFMA GEMM [20480x512] x [1024x512]^T with fused
// exp(w*(cs+1e-6)+b) row-sum epilogue -> atomicAdd rowsum[20480].
// 128x128 tile, BK=32, 4 waves (2x2 of 64x64), global_load_lds width 16,
// XOR k-chunk swizzle so ds_read_b128 is <=2-way bank-conflicted.
// ---------------------------------------------------------------------------
__device__ __forceinline__ void async_copy16(const void* g, void* l) {
    __builtin_amdgcn_global_load_lds(
        (const __attribute__((address_space(1))) void*)g,
        (__attribute__((address_space(3))) void*)l, 16, 0, 0);
}

__global__ __launch_bounds__(256) void gemm_exp(const u16* __restrict__ A,
                                                const u16* __restrict__ Bc,
                                                const float* __restrict__ wp,
                                                const float* __restrict__ bp,
                                                float* __restrict__ rowsum) {
    __shared__ u16 As[128 * 32];   // 8 KB, row-major [row][k], k-chunks XOR-swizzled
    __shared__ u16 Bs[128 * 32];   // 8 KB, [col][k]
    const int t = threadIdx.x;
    const int lane = t & 63, wv = t >> 6;
    const int ml = lane & 15, q = lane >> 4;
    const int wm = wv >> 1, wn = wv & 1;
    const int tileM = blockIdx.x;    // 0..159
    const int tileN = blockIdx.y;    // 0..7

    const float w = *wp, bb = *bp;

    const int c0 = t, c1 = t + 256;
    const int r0 = c0 >> 2, kg0 = (c0 & 3) ^ ((r0 >> 1) & 3);
    const int r1 = c1 >> 2, kg1 = (c1 & 3) ^ ((r1 >> 1) & 3);
    const u16* Ag = A + (size_t)tileM * 128 * DEMB;
    const u16* Bg = Bc + (size_t)tileN * 128 * DEMB;
    u16* as0 = As + c0 * 8; u16* as1 = As + c1 * 8;
    u16* bs0 = Bs + c0 * 8; u16* bs1 = Bs + c1 * 8;

    int ar[4], br[4];
#pragma unroll
    for (int i = 0; i < 4; ++i) {
        int r = wm * 64 + i * 16 + ml;
        ar[i] = r * 32 + ((q ^ ((r >> 1) & 3)) << 3);
        int c = wn * 64 + i * 16 + ml;
        br[i] = c * 32 + ((q ^ ((c >> 1) & 3)) << 3);
    }

    f32x4 acc[4][4];
#pragma unroll
    for (int i = 0; i < 4; ++i)
#pragma unroll
        for (int j = 0; j < 4; ++j) acc[i][j] = (f32x4){0.f, 0.f, 0.f, 0.f};

    for (int kt = 0; kt < DEMB; kt += 32) {
        __syncthreads();
        async_copy16(Ag + (size_t)r0 * DEMB + kt + kg0 * 8, as0);
        async_copy16(Ag + (size_t)r1 * DEMB + kt + kg1 * 8, as1);
        async_copy16(Bg + (size_t)r0 * DEMB + kt + kg0 * 8, bs0);
        async_copy16(Bg + (size_t)r1 * DEMB + kt + kg1 * 8, bs1);
        __syncthreads();

        bf16x8 af[4], bfv[4];
#pragma unroll
        for (int i = 0; i < 4; ++i) af[i] = *(const bf16x8*)(As + ar[i]);
#pragma unroll
        for (int j = 0; j < 4; ++j) bfv[j] = *(const bf16x8*)(Bs + br[j]);
#pragma unroll
        for (int i = 0; i < 4; ++i)
#pragma unroll
            for (int j = 0; j < 4; ++j)
                acc[i][j] = __builtin_amdgcn_mfma_f32_16x16x32_bf16(af[i], bfv[j], acc[i][j], 0, 0, 0);
    }

    // epilogue: exp + row-sum. C/D layout: col = lane&15, row = q*4 + reg.
#pragma unroll
    for (int i = 0; i < 4; ++i) {
        float s0 = 0.f, s1 = 0.f, s2 = 0.f, s3 = 0.f;
#pragma unroll
        for (int j = 0; j < 4; ++j) {
            s0 += __expf(fmaf(w, acc[i][j][0] + 1e-6f, bb));
            s1 += __expf(fmaf(w, acc[i][j][1] + 1e-6f, bb));
            s2 += __expf(fmaf(w, acc[i][j][2] + 1e-6f, bb));
            s3 += __expf(fmaf(w, acc[i][j][3] + 1e-6f, bb));
        }
#pragma unroll
        for (int o = 1; o < 16; o <<= 1) {
            s0 += __shfl_xor(s0, o); s1 += __shfl_xor(s1, o);
            s2 += __shfl_xor(s2, o); s3 += __shfl_xor(s3, o);
        }
        if (ml < 4) {
            float sv = (ml == 0) ? s0 : (ml == 1) ? s1 : (ml == 2) ? s2 : s3;
            int grow = tileM * 128 + wm * 64 + i * 16 + q * 4 + ml;
            atomicAdd(&rowsum[grow], sv);
        }
    }
}

// ---------------------------------------------------------------------------
// Kernel 3: per-row diagonal fixup + log + final reduction.
// ---------------------------------------------------------------------------
__global__ __launch_bounds__(256) void finalize(const float* __restrict__ rowsum,
                                                const float* __restrict__ diag,
                                                const float* __restrict__ csd,
                                                const float* __restrict__ wp,
                                                const float* __restrict__ bp,
                                                float* __restrict__ out) {
    __shared__ float s_red[4];
    const int r = blockIdx.x * 256 + threadIdx.x;   // 80*256 == 20480 exactly
    const float w = *wp, bb = *bp;
    const float dg = diag[r];
    const float pos = fmaf(w, dg + 1e-6f, bb);
    const float S = rowsum[r] - __expf(fmaf(w, csd[r] + 1e-6f, bb)) + __expf(pos);
    float term = logf(S + 1e-6f) - pos;
    const int lane = threadIdx.x & 63, wv = threadIdx.x >> 6;
#pragma unroll
    for (int o = 32; o; o >>= 1) term += __shfl_xor(term, o);
    if (lane == 0) s_red[wv] = term;
    __syncthreads();
    if (threadIdx.x == 0) atomicAdd(out, s_red[0] + s_red[1] + s_red[2] + s_red[3]);
}

extern "C" void kernel_launch(void* const* d_in, const int* in_sizes, int n_in,
                              void* d_out, int out_size, void* d_ws, size_t ws_size,
                              hipStream_t stream) {
    const float* E = (const float*)d_in[0];
    const float* wp = (const float*)d_in[1];
    const float* bp = (const float*)d_in[2];
    float* out = (float*)d_out;

    char* ws = (char*)d_ws;
    u16* A     = (u16*)(ws);                       // 20480*512*2 = 20,971,520 B
    u16* Bc    = (u16*)(ws + 20971520);            //  1024*512*2 =  1,048,576 B
    float* S   = (float*)(ws + 22020096);          //  1024*512*4 =  2,097,152 B
    float* ssg = (float*)(ws + 24117248);          //  1024*2*4   =      8,192 B
    float* dg  = (float*)(ws + 24125440);          // 20480*4
    float* cs  = (float*)(ws + 24207360);          // 20480*4
    float* rs  = (float*)(ws + 24289280);          // 20480*4

    sums_k<<<NSPK, 256, 0, stream>>>(E, S, Bc, ssg, rs, out);
    rowprep_k<<<5120, 256, 0, stream>>>(E, S, ssg, A, dg, cs);
    gemm_exp<<<dim3(160, 8), 256, 0, stream>>>(A, Bc, wp, bp, rs);
    finalize<<<80, 256, 0, stream>>>(rs, dg, cs, wp, bp, out);
}

// Round 3
// 120.948 us; speedup vs baseline: 1.2812x; 1.0325x over previous
//
#include <hip/hip_runtime.h>
#include <hip/hip_bf16.h>

typedef unsigned short u16;
typedef unsigned int u32;
typedef __bf16 bf16x8 __attribute__((ext_vector_type(8)));
typedef float f32x4 __attribute__((ext_vector_type(4)));

#define NSPK 1024
#define NUTT 20
#define DEMB 512
#define NROW (NSPK * NUTT)   // 20480

__device__ __forceinline__ u16 f2bf(float x) {
    union { float f; u32 u; } v; v.f = x;
    u32 r = (v.u + 0x7fffu + ((v.u >> 16) & 1u)) >> 16;   // RNE
    return (u16)r;
}

// ---------------------------------------------------------------------------
// Fused prep: one block (4 waves) per speaker; wave wv owns rows 5wv..5wv+4,
// lane owns dims 8l..8l+7. Reads E ONCE. One barrier (cross-wave sum of s).
// Emits bf16 e_n rows (A), bf16 c_n (Bc), fp32 diag/csd; zeroes rs and out.
//   ee = e.e, es = e.s  =>  diag = (es-ee)/(||e||*max(||s-e||,19e-8)),
//   csd = es * rne * rc/20  (e_n . c_n in fp32 domain; validated R2, absmax 0)
// ---------------------------------------------------------------------------
__global__ __launch_bounds__(256) void prep_f(const float* __restrict__ E,
                                              u16* __restrict__ A,
                                              u16* __restrict__ Bc,
                                              float* __restrict__ diag,
                                              float* __restrict__ csd,
                                              float* __restrict__ rs,
                                              float* __restrict__ out) {
    __shared__ float sbuf[4][DEMB];
    const int t = threadIdx.x, lane = t & 63, wv = t >> 6;
    const int n = blockIdx.x;
    const float* Eb = E + (size_t)n * (NUTT * DEMB) + (size_t)(wv * 5) * DEMB + lane * 8;

    float4 e0[5], e1[5];
    float4 p0 = {0, 0, 0, 0}, p1 = {0, 0, 0, 0};
#pragma unroll
    for (int i = 0; i < 5; ++i) {
        e0[i] = *(const float4*)(Eb + (size_t)i * DEMB);
        e1[i] = *(const float4*)(Eb + (size_t)i * DEMB + 4);
        p0.x += e0[i].x; p0.y += e0[i].y; p0.z += e0[i].z; p0.w += e0[i].w;
        p1.x += e1[i].x; p1.y += e1[i].y; p1.z += e1[i].z; p1.w += e1[i].w;
    }
    *(float4*)(&sbuf[wv][lane * 8])     = p0;
    *(float4*)(&sbuf[wv][lane * 8 + 4]) = p1;
    __syncthreads();

    float4 s0 = {0, 0, 0, 0}, s1 = {0, 0, 0, 0};
#pragma unroll
    for (int k = 0; k < 4; ++k) {
        float4 a = *(const float4*)(&sbuf[k][lane * 8]);
        float4 b = *(const float4*)(&sbuf[k][lane * 8 + 4]);
        s0.x += a.x; s0.y += a.y; s0.z += a.z; s0.w += a.w;
        s1.x += b.x; s1.y += b.y; s1.z += b.z; s1.w += b.w;
    }

    float ls = s0.x*s0.x + s0.y*s0.y + s0.z*s0.z + s0.w*s0.w
             + s1.x*s1.x + s1.y*s1.y + s1.z*s1.z + s1.w*s1.w;
#pragma unroll
    for (int o = 32; o; o >>= 1) ls += __shfl_xor(ls, o);
    const float ss = ls;                                   // ||s||^2
    const float rc = 1.0f / fmaxf(sqrtf(ss) * 0.05f, 1e-8f);   // 1/max(||c||,eps)
    const float g  = rc * 0.05f;                           // rc/20

    union { u16 h[8]; uint4 q; } ck;
    ck.h[0] = f2bf(s0.x * g); ck.h[1] = f2bf(s0.y * g);
    ck.h[2] = f2bf(s0.z * g); ck.h[3] = f2bf(s0.w * g);
    ck.h[4] = f2bf(s1.x * g); ck.h[5] = f2bf(s1.y * g);
    ck.h[6] = f2bf(s1.z * g); ck.h[7] = f2bf(s1.w * g);
    ((uint4*)(Bc + (size_t)n * DEMB))[lane] = ck.q;

#pragma unroll
    for (int i = 0; i < 5; ++i) {
        float ee = e0[i].x*e0[i].x + e0[i].y*e0[i].y + e0[i].z*e0[i].z + e0[i].w*e0[i].w
                 + e1[i].x*e1[i].x + e1[i].y*e1[i].y + e1[i].z*e1[i].z + e1[i].w*e1[i].w;
        float es = e0[i].x*s0.x + e0[i].y*s0.y + e0[i].z*s0.z + e0[i].w*s0.w
                 + e1[i].x*s1.x + e1[i].y*s1.y + e1[i].z*s1.z + e1[i].w*s1.w;
#pragma unroll
        for (int o = 32; o; o >>= 1) { ee += __shfl_xor(ee, o); es += __shfl_xor(es, o); }

        const float rne = 1.0f / fmaxf(sqrtf(ee), 1e-8f);
        const float pxx = ss - 2.f * es + ee;              // ||s-e||^2
        const float dg  = (es - ee) * rne / fmaxf(sqrtf(pxx), 1.9e-7f);

        const int r = n * NUTT + wv * 5 + i;
        union { u16 h[8]; uint4 q; } pk;
        pk.h[0] = f2bf(e0[i].x * rne); pk.h[1] = f2bf(e0[i].y * rne);
        pk.h[2] = f2bf(e0[i].z * rne); pk.h[3] = f2bf(e0[i].w * rne);
        pk.h[4] = f2bf(e1[i].x * rne); pk.h[5] = f2bf(e1[i].y * rne);
        pk.h[6] = f2bf(e1[i].z * rne); pk.h[7] = f2bf(e1[i].w * rne);
        ((uint4*)(A + (size_t)r * DEMB))[lane] = pk.q;
        if (lane == 0) {
            diag[r] = dg;
            csd[r]  = es * g * rne;
        }
    }

    if (t < NUTT) rs[n * NUTT + t] = 0.f;
    if (n == 0 && t == 0) out[0] = 0.f;
}

// ---------------------------------------------------------------------------
// GEMM [20480x512] x [1024x512]^T, bf16 MFMA, fused exp row-sum epilogue.
// 128x128 tile, BK=64 (8 k-iters, half the barriers of R2), 4 waves (2x2 of
// 64x64), global_load_lds width 16, mod-8 XOR k-chunk swizzle (2-way = free).
// LDS 32 KB -> 5 blocks/CU, grid 1280 = 5/CU exactly.
// ---------------------------------------------------------------------------
__device__ __forceinline__ void async_copy16(const void* g, void* l) {
    __builtin_amdgcn_global_load_lds(
        (const __attribute__((address_space(1))) void*)g,
        (__attribute__((address_space(3))) void*)l, 16, 0, 0);
}

__global__ __launch_bounds__(256) void gemm_exp(const u16* __restrict__ A,
                                                const u16* __restrict__ Bc,
                                                const float* __restrict__ wp,
                                                const float* __restrict__ bp,
                                                float* __restrict__ rowsum) {
    __shared__ u16 As[128 * 64];   // 16 KB, [row][k-slab 64], chunks XOR-swizzled
    __shared__ u16 Bs[128 * 64];   // 16 KB
    const int t = threadIdx.x;
    const int lane = t & 63, wv = t >> 6;
    const int ml = lane & 15, q = lane >> 4;
    const int wm = wv >> 1, wn = wv & 1;
    const int tileM = blockIdx.x;    // 0..159
    const int tileN = blockIdx.y;    // 0..7

    const float w = *wp, bb = *bp;

    const u16* Ag = A + (size_t)tileM * 128 * DEMB;
    const u16* Bg = Bc + (size_t)tileN * 128 * DEMB;

    // staging: 1024 16B-chunks per matrix per k-iter; thread t owns chunks t+256j.
    // chunk c -> row r=c>>3, stored slot c&7, logical k-group (c&7)^(r&7).
    const u16* asrc[4]; const u16* bsrc[4]; u16* adst[4]; u16* bdst[4];
#pragma unroll
    for (int j = 0; j < 4; ++j) {
        const int c = t + 256 * j;
        const int r = c >> 3, kg = (c & 7) ^ (r & 7);
        asrc[j] = Ag + (size_t)r * DEMB + kg * 8;  adst[j] = As + c * 8;
        bsrc[j] = Bg + (size_t)r * DEMB + kg * 8;  bdst[j] = Bs + c * 8;
    }

    // fragment offsets (u16 units), loop-invariant: row r, k-half h, quad q
    int aoff[2][4], boff[2][4];
#pragma unroll
    for (int i = 0; i < 4; ++i) {
        const int r = wm * 64 + i * 16 + ml;
        const int c = wn * 64 + i * 16 + ml;
#pragma unroll
        for (int h = 0; h < 2; ++h) {
            aoff[h][i] = r * 64 + ((((h << 2) | q) ^ (r & 7)) << 3);
            boff[h][i] = c * 64 + ((((h << 2) | q) ^ (c & 7)) << 3);
        }
    }

    f32x4 acc[4][4];
#pragma unroll
    for (int i = 0; i < 4; ++i)
#pragma unroll
        for (int j = 0; j < 4; ++j) acc[i][j] = (f32x4){0.f, 0.f, 0.f, 0.f};

    for (int kt = 0; kt < DEMB; kt += 64) {
        __syncthreads();
#pragma unroll
        for (int j = 0; j < 4; ++j) async_copy16(asrc[j] + kt, adst[j]);
#pragma unroll
        for (int j = 0; j < 4; ++j) async_copy16(bsrc[j] + kt, bdst[j]);
        __syncthreads();

#pragma unroll
        for (int h = 0; h < 2; ++h) {
            bf16x8 af[4], bfv[4];
#pragma unroll
            for (int i = 0; i < 4; ++i) af[i]  = *(const bf16x8*)(As + aoff[h][i]);
#pragma unroll
            for (int j = 0; j < 4; ++j) bfv[j] = *(const bf16x8*)(Bs + boff[h][j]);
#pragma unroll
            for (int i = 0; i < 4; ++i)
#pragma unroll
                for (int j = 0; j < 4; ++j)
                    acc[i][j] = __builtin_amdgcn_mfma_f32_16x16x32_bf16(af[i], bfv[j], acc[i][j], 0, 0, 0);
        }
    }

    // epilogue: exp + row-sum. C/D layout: col = lane&15, row = q*4 + reg.
#pragma unroll
    for (int i = 0; i < 4; ++i) {
        float s0 = 0.f, s1 = 0.f, s2 = 0.f, s3 = 0.f;
#pragma unroll
        for (int j = 0; j < 4; ++j) {
            s0 += __expf(fmaf(w, acc[i][j][0] + 1e-6f, bb));
            s1 += __expf(fmaf(w, acc[i][j][1] + 1e-6f, bb));
            s2 += __expf(fmaf(w, acc[i][j][2] + 1e-6f, bb));
            s3 += __expf(fmaf(w, acc[i][j][3] + 1e-6f, bb));
        }
#pragma unroll
        for (int o = 1; o < 16; o <<= 1) {
            s0 += __shfl_xor(s0, o); s1 += __shfl_xor(s1, o);
            s2 += __shfl_xor(s2, o); s3 += __shfl_xor(s3, o);
        }
        if (ml < 4) {
            float sv = (ml == 0) ? s0 : (ml == 1) ? s1 : (ml == 2) ? s2 : s3;
            int grow = tileM * 128 + wm * 64 + i * 16 + q * 4 + ml;
            atomicAdd(&rowsum[grow], sv);
        }
    }
}

// ---------------------------------------------------------------------------
// Finalize: per-row diagonal fixup + log + reduction.
// ---------------------------------------------------------------------------
__global__ __launch_bounds__(256) void finalize(const float* __restrict__ rowsum,
                                                const float* __restrict__ diag,
                                                const float* __restrict__ csd,
                                                const float* __restrict__ wp,
                                                const float* __restrict__ bp,
                                                float* __restrict__ out) {
    __shared__ float s_red[4];
    const int r = blockIdx.x * 256 + threadIdx.x;   // 80*256 == 20480 exactly
    const float w = *wp, bb = *bp;
    const float dg = diag[r];
    const float pos = fmaf(w, dg + 1e-6f, bb);
    const float S = rowsum[r] - __expf(fmaf(w, csd[r] + 1e-6f, bb)) + __expf(pos);
    float term = logf(S + 1e-6f) - pos;
    const int lane = threadIdx.x & 63, wv = threadIdx.x >> 6;
#pragma unroll
    for (int o = 32; o; o >>= 1) term += __shfl_xor(term, o);
    if (lane == 0) s_red[wv] = term;
    __syncthreads();
    if (threadIdx.x == 0) atomicAdd(out, s_red[0] + s_red[1] + s_red[2] + s_red[3]);
}

extern "C" void kernel_launch(void* const* d_in, const int* in_sizes, int n_in,
                              void* d_out, int out_size, void* d_ws, size_t ws_size,
                              hipStream_t stream) {
    const float* E = (const float*)d_in[0];
    const float* wp = (const float*)d_in[1];
    const float* bp = (const float*)d_in[2];
    float* out = (float*)d_out;

    char* ws = (char*)d_ws;
    u16* A     = (u16*)(ws);                       // 20480*512*2 = 20,971,520 B
    u16* Bc    = (u16*)(ws + 20971520);            //  1024*512*2 =  1,048,576 B
    float* dg  = (float*)(ws + 22020096);          // 20480*4
    float* cs  = (float*)(ws + 22102016);          // 20480*4
    float* rs  = (float*)(ws + 22183936);          // 20480*4

    prep_f<<<NSPK, 256, 0, stream>>>(E, A, Bc, dg, cs, rs, out);
    gemm_exp<<<dim3(160, 8), 256, 0, stream>>>(A, Bc, wp, bp, rs);
    finalize<<<80, 256, 0, stream>>>(rs, dg, cs, wp, bp, out);
}

// Round 4
// 109.597 us; speedup vs baseline: 1.4139x; 1.1036x over previous
//
#include <hip/hip_runtime.h>
#include <hip/hip_bf16.h>

typedef unsigned short u16;
typedef unsigned int u32;
typedef unsigned char u8;
typedef int i32x8 __attribute__((ext_vector_type(8)));
typedef float f32x4 __attribute__((ext_vector_type(4)));

#define NSPK 1024
#define NUTT 20
#define DEMB 512
#define NROW (NSPK * NUTT)   // 20480

// pack 8 fp32 -> 8 fp8 e4m3 bytes (HW cvt, gfx950 OCP format — same format MFMA eats)
__device__ __forceinline__ uint2 pk_fp8x8(float a, float b, float c, float d,
                                          float e, float f, float g, float h) {
    int lo = __builtin_amdgcn_cvt_pk_fp8_f32(a, b, 0, 0);
    lo = __builtin_amdgcn_cvt_pk_fp8_f32(c, d, lo, 1);
    int hi = __builtin_amdgcn_cvt_pk_fp8_f32(e, f, 0, 0);
    hi = __builtin_amdgcn_cvt_pk_fp8_f32(g, h, hi, 1);
    return make_uint2((u32)lo, (u32)hi);
}

// ---------------------------------------------------------------------------
// Fused prep: one block per speaker; wave wv owns rows 5wv..5wv+4, lane owns
// dims 8l..8l+7. Reads E once, one barrier. Emits FP8 e_n rows (A), FP8 c_n
// (Bc), fp32 diag/csd; zeroes rs and out. Math identical to R3 (absmax 0.0),
// only the matmul-operand precision changes.
// ---------------------------------------------------------------------------
__global__ __launch_bounds__(256) void prep_f(const float* __restrict__ E,
                                              u8* __restrict__ A,
                                              u8* __restrict__ Bc,
                                              float* __restrict__ diag,
                                              float* __restrict__ csd,
                                              float* __restrict__ rs,
                                              float* __restrict__ out) {
    __shared__ float sbuf[4][DEMB];
    const int t = threadIdx.x, lane = t & 63, wv = t >> 6;
    const int n = blockIdx.x;
    const float* Eb = E + (size_t)n * (NUTT * DEMB) + (size_t)(wv * 5) * DEMB + lane * 8;

    float4 e0[5], e1[5];
    float4 p0 = {0, 0, 0, 0}, p1 = {0, 0, 0, 0};
#pragma unroll
    for (int i = 0; i < 5; ++i) {
        e0[i] = *(const float4*)(Eb + (size_t)i * DEMB);
        e1[i] = *(const float4*)(Eb + (size_t)i * DEMB + 4);
        p0.x += e0[i].x; p0.y += e0[i].y; p0.z += e0[i].z; p0.w += e0[i].w;
        p1.x += e1[i].x; p1.y += e1[i].y; p1.z += e1[i].z; p1.w += e1[i].w;
    }
    *(float4*)(&sbuf[wv][lane * 8])     = p0;
    *(float4*)(&sbuf[wv][lane * 8 + 4]) = p1;
    __syncthreads();

    float4 s0 = {0, 0, 0, 0}, s1 = {0, 0, 0, 0};
#pragma unroll
    for (int k = 0; k < 4; ++k) {
        float4 a = *(const float4*)(&sbuf[k][lane * 8]);
        float4 b = *(const float4*)(&sbuf[k][lane * 8 + 4]);
        s0.x += a.x; s0.y += a.y; s0.z += a.z; s0.w += a.w;
        s1.x += b.x; s1.y += b.y; s1.z += b.z; s1.w += b.w;
    }

    float ls = s0.x*s0.x + s0.y*s0.y + s0.z*s0.z + s0.w*s0.w
             + s1.x*s1.x + s1.y*s1.y + s1.z*s1.z + s1.w*s1.w;
#pragma unroll
    for (int o = 32; o; o >>= 1) ls += __shfl_xor(ls, o);
    const float ss = ls;                                       // ||s||^2
    const float rc = 1.0f / fmaxf(sqrtf(ss) * 0.05f, 1e-8f);   // 1/max(||c||,eps)
    const float g  = rc * 0.05f;                               // rc/20

    ((uint2*)(Bc + (size_t)n * DEMB))[lane] =
        pk_fp8x8(s0.x * g, s0.y * g, s0.z * g, s0.w * g,
                 s1.x * g, s1.y * g, s1.z * g, s1.w * g);

#pragma unroll
    for (int i = 0; i < 5; ++i) {
        float ee = e0[i].x*e0[i].x + e0[i].y*e0[i].y + e0[i].z*e0[i].z + e0[i].w*e0[i].w
                 + e1[i].x*e1[i].x + e1[i].y*e1[i].y + e1[i].z*e1[i].z + e1[i].w*e1[i].w;
        float es = e0[i].x*s0.x + e0[i].y*s0.y + e0[i].z*s0.z + e0[i].w*s0.w
                 + e1[i].x*s1.x + e1[i].y*s1.y + e1[i].z*s1.z + e1[i].w*s1.w;
#pragma unroll
        for (int o = 32; o; o >>= 1) { ee += __shfl_xor(ee, o); es += __shfl_xor(es, o); }

        const float rne = 1.0f / fmaxf(sqrtf(ee), 1e-8f);
        const float pxx = ss - 2.f * es + ee;                  // ||s-e||^2
        const float dg  = (es - ee) * rne / fmaxf(sqrtf(pxx), 1.9e-7f);

        const int r = n * NUTT + wv * 5 + i;
        ((uint2*)(A + (size_t)r * DEMB))[lane] =
            pk_fp8x8(e0[i].x * rne, e0[i].y * rne, e0[i].z * rne, e0[i].w * rne,
                     e1[i].x * rne, e1[i].y * rne, e1[i].z * rne, e1[i].w * rne);
        if (lane == 0) {
            diag[r] = dg;
            csd[r]  = es * g * rne;
        }
    }

    if (t < NUTT) rs[n * NUTT + t] = 0.f;
    if (n == 0 && t == 0) out[0] = 0.f;
}

// ---------------------------------------------------------------------------
// MX-FP8 GEMM [20480x512] x [1024x512]^T with fused exp row-sum epilogue.
// mfma_scale_f32_16x16x128_f8f6f4 (unit scales 0x7F = 2^0), 128x128 tile,
// BK=128 -> only FOUR k-iterations (vs 8 bf16), LDS 2x16 KB, 4 waves.
// XOR chunk swizzle (slot = kg ^ (r&7)) keeps global_load_lds dest linear in
// lane (HW requirement) and makes frag ds_read_b128 bank-uniform. Any k-
// permutation applied identically to A and B cancels in the dot product.
// ---------------------------------------------------------------------------
__device__ __forceinline__ void async_copy16(const void* g, void* l) {
    __builtin_amdgcn_global_load_lds(
        (const __attribute__((address_space(1))) void*)g,
        (__attribute__((address_space(3))) void*)l, 16, 0, 0);
}

__global__ __launch_bounds__(256) void gemm_mx(const u8* __restrict__ A,
                                               const u8* __restrict__ Bc,
                                               const float* __restrict__ wp,
                                               const float* __restrict__ bp,
                                               float* __restrict__ rowsum) {
    __shared__ u8 As[128 * 128];   // 16 KB: [row][128 k-bytes], 16B chunks swizzled
    __shared__ u8 Bs[128 * 128];   // 16 KB
    const int t = threadIdx.x;
    const int lane = t & 63, wv = t >> 6;
    const int ml = lane & 15, q = lane >> 4;
    const int wm = wv >> 1, wn = wv & 1;
    const int tileM = blockIdx.x;    // 0..159
    const int tileN = blockIdx.y;    // 0..7

    const float w = *wp, bb = *bp;

    const u8* Ag = A + (size_t)tileM * 128 * DEMB;
    const u8* Bg = Bc + (size_t)tileN * 128 * DEMB;

    // staging: 1024 16B chunks per matrix per k-iter; thread t owns chunks
    // c = t+256j. c -> row r=c>>3, dest slot c&7 (LINEAR dest = base+lane*16),
    // source k-group kg = (c&7)^(r&7).
    const u8* asrc[4]; const u8* bsrc[4]; u8* adst[4]; u8* bdst[4];
#pragma unroll
    for (int j = 0; j < 4; ++j) {
        const int c = t + 256 * j;
        const int r = c >> 3, kg = (c & 7) ^ (r & 7);
        asrc[j] = Ag + (size_t)r * DEMB + kg * 16;  adst[j] = As + c * 16;
        bsrc[j] = Bg + (size_t)r * DEMB + kg * 16;  bdst[j] = Bs + c * 16;
    }

    // fragment read offsets: row r, quad q covers k bytes q*32..q*32+31 =
    // logical chunks 2q, 2q+1 -> slots (2q)^(r&7), (2q+1)^(r&7).
    int a0[4], a1[4], b0[4], b1[4];
#pragma unroll
    for (int i = 0; i < 4; ++i) {
        const int r = wm * 64 + i * 16 + ml;
        const int c = wn * 64 + i * 16 + ml;
        a0[i] = r * 128 + (((2 * q)     ^ (r & 7)) << 4);
        a1[i] = r * 128 + (((2 * q + 1) ^ (r & 7)) << 4);
        b0[i] = c * 128 + (((2 * q)     ^ (c & 7)) << 4);
        b1[i] = c * 128 + (((2 * q + 1) ^ (c & 7)) << 4);
    }

    f32x4 acc[4][4];
#pragma unroll
    for (int i = 0; i < 4; ++i)
#pragma unroll
        for (int j = 0; j < 4; ++j) acc[i][j] = (f32x4){0.f, 0.f, 0.f, 0.f};

    for (int kt = 0; kt < DEMB; kt += 128) {
        __syncthreads();
#pragma unroll
        for (int j = 0; j < 4; ++j) async_copy16(asrc[j] + kt, adst[j]);
#pragma unroll
        for (int j = 0; j < 4; ++j) async_copy16(bsrc[j] + kt, bdst[j]);
        __syncthreads();

        i32x8 af[4], bf[4];
#pragma unroll
        for (int i = 0; i < 4; ++i) {
            uint4 x = *(const uint4*)(As + a0[i]);
            uint4 y = *(const uint4*)(As + a1[i]);
            af[i] = (i32x8){(int)x.x, (int)x.y, (int)x.z, (int)x.w,
                            (int)y.x, (int)y.y, (int)y.z, (int)y.w};
        }
#pragma unroll
        for (int j = 0; j < 4; ++j) {
            uint4 x = *(const uint4*)(Bs + b0[j]);
            uint4 y = *(const uint4*)(Bs + b1[j]);
            bf[j] = (i32x8){(int)x.x, (int)x.y, (int)x.z, (int)x.w,
                            (int)y.x, (int)y.y, (int)y.z, (int)y.w};
        }
#pragma unroll
        for (int i = 0; i < 4; ++i)
#pragma unroll
            for (int j = 0; j < 4; ++j)
                acc[i][j] = __builtin_amdgcn_mfma_scale_f32_16x16x128_f8f6f4(
                    af[i], bf[j], acc[i][j], 0, 0,           // cbsz=fp8, blgp=fp8
                    0, 0x7F7F7F7F, 0, 0x7F7F7F7F);           // unit scales (E8M0 127)
    }

    // epilogue: exp + row-sum. C/D layout (shape-determined): col=lane&15,
    // row = q*4 + reg.
#pragma unroll
    for (int i = 0; i < 4; ++i) {
        float s0 = 0.f, s1 = 0.f, s2 = 0.f, s3 = 0.f;
#pragma unroll
        for (int j = 0; j < 4; ++j) {
            s0 += __expf(fmaf(w, acc[i][j][0] + 1e-6f, bb));
            s1 += __expf(fmaf(w, acc[i][j][1] + 1e-6f, bb));
            s2 += __expf(fmaf(w, acc[i][j][2] + 1e-6f, bb));
            s3 += __expf(fmaf(w, acc[i][j][3] + 1e-6f, bb));
        }
#pragma unroll
        for (int o = 1; o < 16; o <<= 1) {
            s0 += __shfl_xor(s0, o); s1 += __shfl_xor(s1, o);
            s2 += __shfl_xor(s2, o); s3 += __shfl_xor(s3, o);
        }
        if (ml < 4) {
            float sv = (ml == 0) ? s0 : (ml == 1) ? s1 : (ml == 2) ? s2 : s3;
            int grow = tileM * 128 + wm * 64 + i * 16 + q * 4 + ml;
            atomicAdd(&rowsum[grow], sv);
        }
    }
}

// ---------------------------------------------------------------------------
// Finalize: per-row diagonal fixup + log + reduction.
// ---------------------------------------------------------------------------
__global__ __launch_bounds__(256) void finalize(const float* __restrict__ rowsum,
                                                const float* __restrict__ diag,
                                                const float* __restrict__ csd,
                                                const float* __restrict__ wp,
                                                const float* __restrict__ bp,
                                                float* __restrict__ out) {
    __shared__ float s_red[4];
    const int r = blockIdx.x * 256 + threadIdx.x;   // 80*256 == 20480 exactly
    const float w = *wp, bb = *bp;
    const float dg = diag[r];
    const float pos = fmaf(w, dg + 1e-6f, bb);
    const float S = rowsum[r] - __expf(fmaf(w, csd[r] + 1e-6f, bb)) + __expf(pos);
    float term = logf(S + 1e-6f) - pos;
    const int lane = threadIdx.x & 63, wv = threadIdx.x >> 6;
#pragma unroll
    for (int o = 32; o; o >>= 1) term += __shfl_xor(term, o);
    if (lane == 0) s_red[wv] = term;
    __syncthreads();
    if (threadIdx.x == 0) atomicAdd(out, s_red[0] + s_red[1] + s_red[2] + s_red[3]);
}

extern "C" void kernel_launch(void* const* d_in, const int* in_sizes, int n_in,
                              void* d_out, int out_size, void* d_ws, size_t ws_size,
                              hipStream_t stream) {
    const float* E = (const float*)d_in[0];
    const float* wp = (const float*)d_in[1];
    const float* bp = (const float*)d_in[2];
    float* out = (float*)d_out;

    char* ws = (char*)d_ws;
    u8* A      = (u8*)(ws);                        // 20480*512   = 10,485,760 B
    u8* Bc     = (u8*)(ws + 10485760);             //  1024*512   =     524,288 B
    float* dg  = (float*)(ws + 11010048);          // 20480*4
    float* cs  = (float*)(ws + 11091968);          // 20480*4
    float* rs  = (float*)(ws + 11173888);          // 20480*4

    prep_f<<<NSPK, 256, 0, stream>>>(E, A, Bc, dg, cs, rs, out);
    gemm_mx<<<dim3(160, 8), 256, 0, stream>>>(A, Bc, wp, bp, rs);
    finalize<<<80, 256, 0, stream>>>(rs, dg, cs, wp, bp, out);
}